// Round 6
// baseline (601.810 us; speedup 1.0000x reference)
//
#include <hip/hip_runtime.h>
#include <hip/hip_cooperative_groups.h>
#include <hip/hip_bf16.h>

// Problem constants
#define NN 100000
#define DD 128
#define BB 4096
#define KK 64
#define HH 256
#define EE 128

typedef __bf16 bf16x8 __attribute__((ext_vector_type(8)));
typedef float f32x4 __attribute__((ext_vector_type(4)));

// ---- bf16 frag region (element offsets). frag = 64 lanes x 16B = 512 elems.
// B-frag layout for mfma_f32_16x16x32_bf16: lane l holds B[k][n] with
// n = nt*16 + (l&15), k = kk*32 + (l>>4)*8 + j, j=0..7.
#define EL_W1A   0        // 16nt x 4kk = 64 frags   (W1a rows 0..255, K=128)
#define EL_WHH   32768    // 64nt x 8kk = 512 frags  (Whh, K=256)
#define EL_W2A   294912   // 16nt x 4kk = 64 frags   (W2a, K=128)
#define EL_WFOLD 327680   // 64nt x 8kk = 512 frags  (Wih@W1b, K=256)
#define EL_TM    589824   // 16nt x 8kk = 128 frags  (t-matrix, K=256)
// frag region ends at elem 655360 = byte 0x140000

// ---- workspace regions (byte offsets) ----
#define BOFF_GB2   0x140000   // fp32[1024]  bih+bhh+Wih@b1b
#define BOFF_W1COL 0x141000   // fp32[256]   W1a[:,128]
#define BOFF_W2COL 0x141400   // fp32[256]   W2a[:,128]
#define BOFF_TB    0x141800   // fp32[256]   W2b^T b3
#define BOFF_CVEC  0x141C00   // fp32[256]   W3^T b2b
#define BOFF_CBIAS 0x142000   // fp32[1]     b2b.b3
#define BOFF_CONST 0x142400   // fp32[4096]
#define BOFF_X1    0x147000   // x1 bf16[4096][256] (2MB)
#define BOFF_HB    0x347000   // h  bf16[4096][256] (2MB)
#define BOFF_T     0x547000   // t  bf16[4096][256] (2MB)

#define N_PRE 1313

__device__ __forceinline__ float sigmoid_f(float x){ return 1.0f/(1.0f+__expf(-x)); }
__device__ __forceinline__ float tanh_f(float x){ return 1.0f - 2.0f/(__expf(2.0f*x)+1.0f); }

__device__ __forceinline__ bf16x8 pack8(float4 a, float4 b){
    bf16x8 v;
    v[0]=(__bf16)a.x; v[1]=(__bf16)a.y; v[2]=(__bf16)a.z; v[3]=(__bf16)a.w;
    v[4]=(__bf16)b.x; v[5]=(__bf16)b.y; v[6]=(__bf16)b.z; v[7]=(__bf16)b.w;
    return v;
}

struct ActP {
    const float *node_pre, *steps, *h0, *c0;
    const float *W1a, *b1a, *W1b, *b1b, *W2a, *W2b, *b2b, *W3, *b3;
    const float *Wih, *Whh, *bih, *bhh;
    const int   *actions0;
    __bf16 *wsbf;
    float  *gb2, *w1col, *w2col, *tb, *cvec, *cbias, *cst;
    __bf16 *x1, *hb, *t;
    float  *out_h, *out_c;
};

// ===================== stage device functions (unit = 1 wave) ==============

// pre: weight swizzles + folded products + bias vectors
__device__ void stage_pre(const ActP& p, int g, int lane, int quad, int l15){
    if (g < 640){           // plain frag swizzles: W1a(64) Whh(512) W2a(64)
        const float* src; int stride, nkk, local; long dst;
        if      (g <  64){ src=p.W1a; stride=129; nkk=4; dst=EL_W1A; local=g;     }
        else if (g < 576){ src=p.Whh; stride=256; nkk=8; dst=EL_WHH; local=g-64;  }
        else             { src=p.W2a; stride=129; nkk=4; dst=EL_W2A; local=g-576; }
        int nt = local / nkk, kk = local % nkk;
        int n = nt*16 + l15, k0 = kk*32 + quad*8;
        bf16x8 v;
#pragma unroll
        for (int j = 0; j < 8; ++j) v[j] = (__bf16)src[(long)n*stride + k0 + j];
        ((bf16x8*)(p.wsbf + dst))[local*64 + lane] = v;
    }
    else if (g < 1152){     // Wfold[g,k] = sum_n Wih[g,n]*W1b[n,k] -> frags
        int c = (g-640)*64 + lane;
        int grow = c >> 5, k8 = c & 31, k0 = k8*8;
        float acc[8] = {0,0,0,0,0,0,0,0};
        const float* wr = p.Wih + (long)grow*128;
        for (int n = 0; n < 128; ++n){
            float w = wr[n];
            const float4* bp = (const float4*)(p.W1b + (long)n*256 + k0);
            float4 b0 = bp[0], b1 = bp[1];
            acc[0] += w*b0.x; acc[1] += w*b0.y; acc[2] += w*b0.z; acc[3] += w*b0.w;
            acc[4] += w*b1.x; acc[5] += w*b1.y; acc[6] += w*b1.z; acc[7] += w*b1.w;
        }
        bf16x8 v;
#pragma unroll
        for (int j = 0; j < 8; ++j) v[j] = (__bf16)acc[j];
        int nt = grow >> 4, l15r = grow & 15, kk = k8 >> 2, qd = k8 & 3;
        ((bf16x8*)(p.wsbf + EL_WFOLD))[(nt*8+kk)*64 + qd*16 + l15r] = v;
    }
    else if (g < 1280){     // Tm[m,h] = sum_e W3[e,m]*W2b[e,h] -> frags
        int c = (g-1152)*64 + lane;
        int hcol = c >> 5, m8 = c & 31, m0 = m8*8;
        float acc[8] = {0,0,0,0,0,0,0,0};
        for (int e = 0; e < 128; ++e){
            float w = p.W2b[(long)e*256 + hcol];
            const float4* wp = (const float4*)(p.W3 + (long)e*256 + m0);
            float4 a0 = wp[0], a1 = wp[1];
            acc[0] += w*a0.x; acc[1] += w*a0.y; acc[2] += w*a0.z; acc[3] += w*a0.w;
            acc[4] += w*a1.x; acc[5] += w*a1.y; acc[6] += w*a1.z; acc[7] += w*a1.w;
        }
        bf16x8 v;
#pragma unroll
        for (int j = 0; j < 8; ++j) v[j] = (__bf16)acc[j];
        int nt = hcol >> 4, l15r = hcol & 15, kk = m8 >> 2, qd = m8 & 3;
        ((bf16x8*)(p.wsbf + EL_TM))[(nt*8+kk)*64 + qd*16 + l15r] = v;
    }
    else if (g < 1296){     // gbias2[g] = bih+bhh + Wih@b1b
        int gi = (g-1280)*64 + lane;
        float s = p.bih[gi] + p.bhh[gi];
        const float* wr = p.Wih + (long)gi*128;
        for (int n = 0; n < 128; ++n) s += wr[n]*p.b1b[n];
        p.gb2[gi] = s;
    }
    else if (g < 1300){ int i = (g-1296)*64 + lane; p.w1col[i] = p.W1a[i*129 + 128]; }
    else if (g < 1304){ int i = (g-1300)*64 + lane; p.w2col[i] = p.W2a[i*129 + 128]; }
    else if (g < 1308){     // tb[h] = sum_e W2b[e,h]*b3[e]
        int i = (g-1304)*64 + lane;
        float s = 0.f;
        for (int e = 0; e < 128; ++e) s += p.W2b[(long)e*256 + i]*p.b3[e];
        p.tb[i] = s;
    }
    else if (g < 1312){     // cvec[m] = sum_e b2b[e]*W3[e,m]
        int i = (g-1308)*64 + lane;
        float s = 0.f;
        for (int e = 0; e < 128; ++e) s += p.b2b[e]*p.W3[(long)e*256 + i];
        p.cvec[i] = s;
    }
    else {                  // cbias = b2b.b3
        float s = p.b2b[lane]*p.b3[lane] + p.b2b[lane+64]*p.b3[lane+64];
#pragma unroll
        for (int m = 1; m < 64; m <<= 1) s += __shfl_xor(s, m, 64);
        if (lane == 0) p.cbias[0] = s;
    }
}

// S1: x1 = relu(a_pre @ W1a^T + b1a + w1col*sb)   (1024 units)
__device__ void stage_s1(const ActP& p, int u, int lane, int quad, int l15){
    int mt = u >> 2, ng = u & 3, m0 = mt*16;
    long arow = p.actions0[m0 + l15];
    bf16x8 af[4];
#pragma unroll
    for (int kk = 0; kk < 4; ++kk){
        const float4* q = (const float4*)(p.node_pre + arow*128 + kk*32 + quad*8);
        af[kk] = pack8(q[0], q[1]);
    }
    float sb_i[4];
#pragma unroll
    for (int i = 0; i < 4; ++i) sb_i[i] = p.steps[m0 + quad*4 + i] * 0.01f;
    const bf16x8* FB = (const bf16x8*)(p.wsbf + EL_W1A);
#pragma unroll
    for (int j = 0; j < 4; ++j){
        int nt = ng*4 + j;
        f32x4 acc = {0.f,0.f,0.f,0.f};
#pragma unroll
        for (int kk = 0; kk < 4; ++kk)
            acc = __builtin_amdgcn_mfma_f32_16x16x32_bf16(af[kk], FB[(nt*4+kk)*64 + lane], acc, 0,0,0);
        int col = nt*16 + l15;
        float bb = p.b1a[col], wc = p.w1col[col];
#pragma unroll
        for (int i = 0; i < 4; ++i)
            p.x1[(long)(m0 + quad*4 + i)*256 + col] = (__bf16)fmaxf(acc[i] + bb + wc*sb_i[i], 0.f);
    }
}

// LSTM: gates = x1@Wfold^T + h0@Whh^T + gbias2; elementwise  (4096 units)
__device__ void stage_lstm(const ActP& p, int u, int lane, int quad, int l15){
    int mt = u >> 4, ct = u & 15, m0 = mt*16;
    bf16x8 af[16];
#pragma unroll
    for (int kk = 0; kk < 8; ++kk)
        af[kk] = *(const bf16x8*)&p.x1[(long)(m0 + l15)*256 + kk*32 + quad*8];
#pragma unroll
    for (int kk = 0; kk < 8; ++kk){
        const float4* hp = (const float4*)(p.h0 + (long)(m0 + l15)*256 + kk*32 + quad*8);
        af[8+kk] = pack8(hp[0], hp[1]);
    }
    const bf16x8* FW = (const bf16x8*)(p.wsbf + EL_WFOLD);
    const bf16x8* FH = (const bf16x8*)(p.wsbf + EL_WHH);
    f32x4 aI = {0.f,0.f,0.f,0.f}, aF = aI, aG = aI, aO = aI;
#pragma unroll 4
    for (int kk = 0; kk < 8; ++kk){
        aI = __builtin_amdgcn_mfma_f32_16x16x32_bf16(af[kk], FW[(( 0+ct)*8+kk)*64 + lane], aI, 0,0,0);
        aF = __builtin_amdgcn_mfma_f32_16x16x32_bf16(af[kk], FW[((16+ct)*8+kk)*64 + lane], aF, 0,0,0);
        aG = __builtin_amdgcn_mfma_f32_16x16x32_bf16(af[kk], FW[((32+ct)*8+kk)*64 + lane], aG, 0,0,0);
        aO = __builtin_amdgcn_mfma_f32_16x16x32_bf16(af[kk], FW[((48+ct)*8+kk)*64 + lane], aO, 0,0,0);
    }
#pragma unroll 4
    for (int kk = 0; kk < 8; ++kk){
        aI = __builtin_amdgcn_mfma_f32_16x16x32_bf16(af[8+kk], FH[(( 0+ct)*8+kk)*64 + lane], aI, 0,0,0);
        aF = __builtin_amdgcn_mfma_f32_16x16x32_bf16(af[8+kk], FH[((16+ct)*8+kk)*64 + lane], aF, 0,0,0);
        aG = __builtin_amdgcn_mfma_f32_16x16x32_bf16(af[8+kk], FH[((32+ct)*8+kk)*64 + lane], aG, 0,0,0);
        aO = __builtin_amdgcn_mfma_f32_16x16x32_bf16(af[8+kk], FH[((48+ct)*8+kk)*64 + lane], aO, 0,0,0);
    }
    int col = ct*16 + l15;
    float bI = p.gb2[col], bF = p.gb2[256+col], bG = p.gb2[512+col], bO = p.gb2[768+col];
#pragma unroll
    for (int i = 0; i < 4; ++i){
        long row = m0 + quad*4 + i;
        float iv = aI[i]+bI, fv = aF[i]+bF, gv = aG[i]+bG, ov = aO[i]+bO;
        float cc = p.c0[row*256 + col];
        float cn = sigmoid_f(fv)*cc + sigmoid_f(iv)*tanh_f(gv);
        float hn = sigmoid_f(ov)*tanh_f(cn);
        p.out_c[row*256 + col] = cn;
        p.out_h[row*256 + col] = hn;
        p.hb[row*256 + col] = (__bf16)hn;
    }
}

// TK: t = h@Tm + tb; cst = h.cvec + cbias   (1024 units)
__device__ void stage_tk(const ActP& p, int u, int lane, int quad, int l15){
    int mt = u >> 2, ng = u & 3, m0 = mt*16;
    bf16x8 af[8];
#pragma unroll
    for (int kk = 0; kk < 8; ++kk)
        af[kk] = *(const bf16x8*)&p.hb[(long)(m0 + l15)*256 + kk*32 + quad*8];
    if (ng == 0){
        float s = 0.f;
#pragma unroll
        for (int kk = 0; kk < 8; ++kk)
#pragma unroll
            for (int j = 0; j < 8; ++j)
                s += p.cvec[kk*32 + quad*8 + j] * (float)af[kk][j];
        s += __shfl_xor(s, 16, 64);
        s += __shfl_xor(s, 32, 64);
        if (lane < 16) p.cst[m0 + l15] = s + p.cbias[0];
    }
    const bf16x8* FB = (const bf16x8*)(p.wsbf + EL_TM);
#pragma unroll
    for (int j = 0; j < 4; ++j){
        int nt = ng*4 + j;
        f32x4 acc = {0.f,0.f,0.f,0.f};
#pragma unroll
        for (int kk = 0; kk < 8; ++kk)
            acc = __builtin_amdgcn_mfma_f32_16x16x32_bf16(af[kk], FB[(nt*8+kk)*64 + lane], acc, 0,0,0);
        int col = nt*16 + l15;
        float bb = p.tb[col];
#pragma unroll
        for (int i = 0; i < 4; ++i)
            p.t[(long)(m0 + quad*4 + i)*256 + col] = (__bf16)(acc[i] + bb);
    }
}

// ===================== cooperative fused act path ==========================
// 512 blocks x 256 threads, 2 blocks/CU guaranteed by __launch_bounds__(256,2).
__global__ __launch_bounds__(256, 2) void coop_act(ActP p)
{
    cooperative_groups::grid_group grid = cooperative_groups::this_grid();
    const int tid = threadIdx.x, lane = tid & 63;
    const int quad = lane >> 4, l15 = lane & 15;
    const int gw = blockIdx.x*4 + (tid >> 6);
    const int TW = gridDim.x*4;

    for (int g = gw; g < N_PRE; g += TW) stage_pre(p, g, lane, quad, l15);
    __threadfence(); grid.sync();
    for (int u = gw; u < 1024; u += TW) stage_s1(p, u, lane, quad, l15);
    __threadfence(); grid.sync();
    for (int u = gw; u < 4096; u += TW) stage_lstm(p, u, lane, quad, l15);
    __threadfence(); grid.sync();
    for (int u = gw; u < 1024; u += TW) stage_tk(p, u, lane, quad, l15);
}

// ---- fallback: same stages as separate 1-wave-per-block kernels -----------
__global__ __launch_bounds__(64) void pre_k (ActP p){ int l = threadIdx.x; stage_pre (p, blockIdx.x, l, l>>4, l&15); }
__global__ __launch_bounds__(64) void s1_k  (ActP p){ int l = threadIdx.x; stage_s1  (p, blockIdx.x, l, l>>4, l&15); }
__global__ __launch_bounds__(64) void lstm_k(ActP p){ int l = threadIdx.x; stage_lstm(p, blockIdx.x, l, l>>4, l&15); }
__global__ __launch_bounds__(64) void tk_k  (ActP p){ int l = threadIdx.x; stage_tk  (p, blockIdx.x, l, l>>4, l&15); }

// ===================== neighbor path (unchanged from R4) ===================
__global__ __launch_bounds__(256) void nei_kernel(
    const float* __restrict__ node_pre, const float* __restrict__ steps,
    const float* __restrict__ b2a, const float* __restrict__ w2col,
    const int* __restrict__ neighbors, const int* __restrict__ deg,
    const __bf16* __restrict__ wsbf, const __bf16* __restrict__ t_bf,
    const float* __restrict__ const_ws, float* __restrict__ out_vals)
{
    __shared__ __bf16 at[64*136];
    __shared__ float t_s[256], bias_s[256], vp[256];

    int tid = threadIdx.x, b = blockIdx.x;
    int degb = deg[b]; if (degb < 1) degb = 1;
    int ntile = (degb + 15) >> 4;
    float sb = steps[b] * 0.01f;
    t_s[tid]    = (float)t_bf[(long)b*256 + tid];
    bias_s[tid] = b2a[tid] + w2col[tid]*sb;
    {
        int r = tid >> 2, sg = tid & 3;
        if (r < ntile*16){
            long nb = neighbors[b*64 + r];
            const float4* sp = (const float4*)(node_pre + nb*128 + sg*32);
#pragma unroll
            for (int q = 0; q < 4; ++q){
                float4 fa = sp[q*2], fb = sp[q*2+1];
                *(bf16x8*)&at[r*136 + sg*32 + q*8] = pack8(fa, fb);
            }
        }
    }

    int wave = tid >> 6, lane = tid & 63, quad = lane >> 4, l15 = lane & 15;
    const bf16x8* FB = (const bf16x8*)(wsbf + EL_W2A);
    bf16x8 bw[16];
#pragma unroll
    for (int j = 0; j < 4; ++j){
        int nt = wave + 4*j;
#pragma unroll
        for (int kk = 0; kk < 4; ++kk) bw[j*4+kk] = FB[(nt*4+kk)*64 + lane];
    }
    __syncthreads();

#pragma unroll 1
    for (int mt = 0; mt < ntile; ++mt){
        bf16x8 af[4];
#pragma unroll
        for (int kk = 0; kk < 4; ++kk)
            af[kk] = *(const bf16x8*)&at[(mt*16 + l15)*136 + kk*32 + quad*8];
        f32x4 ps = {0.f,0.f,0.f,0.f};
#pragma unroll
        for (int j = 0; j < 4; ++j){
            int nt = wave + 4*j;
            f32x4 acc = {0.f,0.f,0.f,0.f};
#pragma unroll
            for (int kk = 0; kk < 4; ++kk)
                acc = __builtin_amdgcn_mfma_f32_16x16x32_bf16(af[kk], bw[j*4+kk], acc, 0,0,0);
            int col = nt*16 + l15;
            float bb = bias_s[col], tv = t_s[col];
#pragma unroll
            for (int i = 0; i < 4; ++i)
                ps[i] += fmaxf(acc[i] + bb, 0.f) * tv;
        }
#pragma unroll
        for (int m = 1; m < 16; m <<= 1){
#pragma unroll
            for (int i = 0; i < 4; ++i) ps[i] += __shfl_xor(ps[i], m, 64);
        }
        if (l15 == 0){
#pragma unroll
            for (int i = 0; i < 4; ++i) vp[wave*64 + mt*16 + quad*4 + i] = ps[i];
        }
    }
    __syncthreads();
    if (tid < 64){
        float v = vp[tid] + vp[64+tid] + vp[128+tid] + vp[192+tid];
        v = (v + const_ws[b]) * 0.08838834764831845f;   // 1/sqrt(128)
        if (tid >= degb) v = 0.f;
        out_vals[(long)b*64 + tid] = v;
    }
}

extern "C" void kernel_launch(void* const* d_in, const int* in_sizes, int n_in,
                              void* d_out, int out_size, void* d_ws, size_t ws_size,
                              hipStream_t stream)
{
    (void)in_sizes; (void)n_in; (void)out_size; (void)ws_size;
    const float* node_pre = (const float*)d_in[0];

    float* out      = (float*)d_out;
    float* out_vals = out;                       // [4096][64]
    float* out_h    = out + (long)BB*KK;         // [4096][256]
    float* out_c    = out_h + (long)BB*HH;       // [4096][256]

    ActP p;
    p.node_pre = node_pre;
    p.steps    = (const float*)d_in[1];
    p.h0       = (const float*)d_in[2];
    p.c0       = (const float*)d_in[3];
    p.W1a      = (const float*)d_in[4];
    p.b1a      = (const float*)d_in[5];
    p.W1b      = (const float*)d_in[6];
    p.b1b      = (const float*)d_in[7];
    p.W2a      = (const float*)d_in[8];
    p.W2b      = (const float*)d_in[10];
    p.b2b      = (const float*)d_in[11];
    p.W3       = (const float*)d_in[12];
    p.b3       = (const float*)d_in[13];
    p.Wih      = (const float*)d_in[14];
    p.Whh      = (const float*)d_in[15];
    p.bih      = (const float*)d_in[16];
    p.bhh      = (const float*)d_in[17];
    p.actions0 = (const int*)d_in[18];
    p.wsbf  = (__bf16*)d_ws;
    p.gb2   = (float*)((char*)d_ws + BOFF_GB2);
    p.w1col = (float*)((char*)d_ws + BOFF_W1COL);
    p.w2col = (float*)((char*)d_ws + BOFF_W2COL);
    p.tb    = (float*)((char*)d_ws + BOFF_TB);
    p.cvec  = (float*)((char*)d_ws + BOFF_CVEC);
    p.cbias = (float*)((char*)d_ws + BOFF_CBIAS);
    p.cst   = (float*)((char*)d_ws + BOFF_CONST);
    p.x1    = (__bf16*)((char*)d_ws + BOFF_X1);
    p.hb    = (__bf16*)((char*)d_ws + BOFF_HB);
    p.t     = (__bf16*)((char*)d_ws + BOFF_T);
    p.out_h = out_h; p.out_c = out_c;

    void* kargs[] = { (void*)&p };
    hipError_t ce = hipLaunchCooperativeKernel(coop_act, dim3(512), dim3(256),
                                               kargs, 0, stream);
    if (ce != hipSuccess){
        // fallback: same stages as separate dispatches (bit-identical math)
        pre_k <<<dim3(N_PRE), dim3(64), 0, stream>>>(p);
        s1_k  <<<dim3(1024),  dim3(64), 0, stream>>>(p);
        lstm_k<<<dim3(4096),  dim3(64), 0, stream>>>(p);
        tk_k  <<<dim3(1024),  dim3(64), 0, stream>>>(p);
    }

    nei_kernel<<<dim3(4096), dim3(256), 0, stream>>>(
        node_pre, p.steps, (const float*)d_in[9],
        (const float*)((char*)d_ws + BOFF_W2COL),
        (const int*)d_in[19], (const int*)d_in[20],
        (const __bf16*)d_ws, (const __bf16*)((char*)d_ws + BOFF_T),
        (const float*)((char*)d_ws + BOFF_CONST), out_vals);
}

// Round 7
// 229.675 us; speedup vs baseline: 2.6203x; 2.6203x over previous
//
#include <hip/hip_runtime.h>
#include <hip/hip_bf16.h>

// Problem constants
#define NN 100000
#define DD 128
#define BB 4096
#define KK 64
#define HH 256
#define EE 128

typedef __bf16 bf16x8 __attribute__((ext_vector_type(8)));
typedef float f32x4 __attribute__((ext_vector_type(4)));

// ---- bf16 frag region (element offsets). frag = 64 lanes x 16B = 512 elems.
// B-frag layout for mfma_f32_16x16x32_bf16: lane l holds B[k][n] with
// n = nt*16 + (l&15), k = kk*32 + (l>>4)*8 + j, j=0..7.
#define EL_W1A   0        // 16nt x 4kk = 64 frags   (W1a rows 0..255, K=128)
#define EL_WHH   32768    // 64nt x 8kk = 512 frags  (Whh, K=256)
#define EL_W2A   294912   // 16nt x 4kk = 64 frags   (W2a, K=128)
#define EL_WFOLD 327680   // 64nt x 8kk = 512 frags  (Wih@W1b, K=256)
#define EL_TM    589824   // 16nt x 8kk = 128 frags  (t-matrix, K=256)
// frag region ends at elem 655360 = byte 0x140000

// ---- workspace regions (byte offsets) ----
#define BOFF_GB2   0x140000   // fp32[1024]  bih+bhh+Wih@b1b
#define BOFF_W1COL 0x141000   // fp32[256]   W1a[:,128]
#define BOFF_W2COL 0x141400   // fp32[256]   W2a[:,128]
#define BOFF_TB    0x141800   // fp32[256]   W2b^T b3
#define BOFF_CVEC  0x141C00   // fp32[256]   W3^T b2b
#define BOFF_CBIAS 0x142000   // fp32[1]     b2b.b3
#define BOFF_CONST 0x142400   // fp32[4096]
#define BOFF_X1    0x147000   // x1 bf16[4096][256] (2MB)
#define BOFF_HB    0x347000   // h  bf16[4096][256] (2MB)
#define BOFF_T     0x547000   // t  bf16[4096][256] (2MB)

#define N_PRE 1313

__device__ __forceinline__ float sigmoid_f(float x){ return 1.0f/(1.0f+__expf(-x)); }
__device__ __forceinline__ float tanh_f(float x){ return 1.0f - 2.0f/(__expf(2.0f*x)+1.0f); }

__device__ __forceinline__ bf16x8 pack8(float4 a, float4 b){
    bf16x8 v;
    v[0]=(__bf16)a.x; v[1]=(__bf16)a.y; v[2]=(__bf16)a.z; v[3]=(__bf16)a.w;
    v[4]=(__bf16)b.x; v[5]=(__bf16)b.y; v[6]=(__bf16)b.z; v[7]=(__bf16)b.w;
    return v;
}

struct ActP {
    const float *node_pre, *steps, *h0, *c0;
    const float *W1a, *b1a, *W1b, *b1b, *W2a, *W2b, *b2b, *W3, *b3;
    const float *Wih, *Whh, *bih, *bhh;
    const int   *actions0;
    __bf16 *wsbf;
    float  *gb2, *w1col, *w2col, *tb, *cvec, *cbias, *cst;
    __bf16 *x1, *hb, *t;
    float  *out_h, *out_c;
};

// ===================== stage device functions (unit = 1 wave) ==============

// pre: weight swizzles + folded products + bias vectors
__device__ void stage_pre(const ActP& p, int g, int lane, int quad, int l15){
    if (g < 640){           // plain frag swizzles: W1a(64) Whh(512) W2a(64)
        const float* src; int stride, nkk, local; long dst;
        if      (g <  64){ src=p.W1a; stride=129; nkk=4; dst=EL_W1A; local=g;     }
        else if (g < 576){ src=p.Whh; stride=256; nkk=8; dst=EL_WHH; local=g-64;  }
        else             { src=p.W2a; stride=129; nkk=4; dst=EL_W2A; local=g-576; }
        int nt = local / nkk, kk = local % nkk;
        int n = nt*16 + l15, k0 = kk*32 + quad*8;
        bf16x8 v;
#pragma unroll
        for (int j = 0; j < 8; ++j) v[j] = (__bf16)src[(long)n*stride + k0 + j];
        ((bf16x8*)(p.wsbf + dst))[local*64 + lane] = v;
    }
    else if (g < 1152){     // Wfold[g,k] = sum_n Wih[g,n]*W1b[n,k] -> frags
        int c = (g-640)*64 + lane;
        int grow = c >> 5, k8 = c & 31, k0 = k8*8;
        float acc[8] = {0,0,0,0,0,0,0,0};
        const float* wr = p.Wih + (long)grow*128;
        for (int n = 0; n < 128; ++n){
            float w = wr[n];
            const float4* bp = (const float4*)(p.W1b + (long)n*256 + k0);
            float4 b0 = bp[0], b1 = bp[1];
            acc[0] += w*b0.x; acc[1] += w*b0.y; acc[2] += w*b0.z; acc[3] += w*b0.w;
            acc[4] += w*b1.x; acc[5] += w*b1.y; acc[6] += w*b1.z; acc[7] += w*b1.w;
        }
        bf16x8 v;
#pragma unroll
        for (int j = 0; j < 8; ++j) v[j] = (__bf16)acc[j];
        int nt = grow >> 4, l15r = grow & 15, kk = k8 >> 2, qd = k8 & 3;
        ((bf16x8*)(p.wsbf + EL_WFOLD))[(nt*8+kk)*64 + qd*16 + l15r] = v;
    }
    else if (g < 1280){     // Tm[m,h] = sum_e W3[e,m]*W2b[e,h] -> frags
        int c = (g-1152)*64 + lane;
        int hcol = c >> 5, m8 = c & 31, m0 = m8*8;
        float acc[8] = {0,0,0,0,0,0,0,0};
        for (int e = 0; e < 128; ++e){
            float w = p.W2b[(long)e*256 + hcol];
            const float4* wp = (const float4*)(p.W3 + (long)e*256 + m0);
            float4 a0 = wp[0], a1 = wp[1];
            acc[0] += w*a0.x; acc[1] += w*a0.y; acc[2] += w*a0.z; acc[3] += w*a0.w;
            acc[4] += w*a1.x; acc[5] += w*a1.y; acc[6] += w*a1.z; acc[7] += w*a1.w;
        }
        bf16x8 v;
#pragma unroll
        for (int j = 0; j < 8; ++j) v[j] = (__bf16)acc[j];
        int nt = hcol >> 4, l15r = hcol & 15, kk = m8 >> 2, qd = m8 & 3;
        ((bf16x8*)(p.wsbf + EL_TM))[(nt*8+kk)*64 + qd*16 + l15r] = v;
    }
    else if (g < 1296){     // gbias2[g] = bih+bhh + Wih@b1b
        int gi = (g-1280)*64 + lane;
        float s = p.bih[gi] + p.bhh[gi];
        const float* wr = p.Wih + (long)gi*128;
        for (int n = 0; n < 128; ++n) s += wr[n]*p.b1b[n];
        p.gb2[gi] = s;
    }
    else if (g < 1300){ int i = (g-1296)*64 + lane; p.w1col[i] = p.W1a[i*129 + 128]; }
    else if (g < 1304){ int i = (g-1300)*64 + lane; p.w2col[i] = p.W2a[i*129 + 128]; }
    else if (g < 1308){     // tb[h] = sum_e W2b[e,h]*b3[e]
        int i = (g-1304)*64 + lane;
        float s = 0.f;
        for (int e = 0; e < 128; ++e) s += p.W2b[(long)e*256 + i]*p.b3[e];
        p.tb[i] = s;
    }
    else if (g < 1312){     // cvec[m] = sum_e b2b[e]*W3[e,m]
        int i = (g-1308)*64 + lane;
        float s = 0.f;
        for (int e = 0; e < 128; ++e) s += p.b2b[e]*p.W3[(long)e*256 + i];
        p.cvec[i] = s;
    }
    else {                  // cbias = b2b.b3
        float s = p.b2b[lane]*p.b3[lane] + p.b2b[lane+64]*p.b3[lane+64];
#pragma unroll
        for (int m = 1; m < 64; m <<= 1) s += __shfl_xor(s, m, 64);
        if (lane == 0) p.cbias[0] = s;
    }
}

// S1: x1 = relu(a_pre @ W1a^T + b1a + w1col*sb)   (1024 units)
__device__ void stage_s1(const ActP& p, int u, int lane, int quad, int l15){
    int mt = u >> 2, ng = u & 3, m0 = mt*16;
    long arow = p.actions0[m0 + l15];
    bf16x8 af[4];
#pragma unroll
    for (int kk = 0; kk < 4; ++kk){
        const float4* q = (const float4*)(p.node_pre + arow*128 + kk*32 + quad*8);
        af[kk] = pack8(q[0], q[1]);
    }
    float sb_i[4];
#pragma unroll
    for (int i = 0; i < 4; ++i) sb_i[i] = p.steps[m0 + quad*4 + i] * 0.01f;
    const bf16x8* FB = (const bf16x8*)(p.wsbf + EL_W1A);
#pragma unroll
    for (int j = 0; j < 4; ++j){
        int nt = ng*4 + j;
        f32x4 acc = {0.f,0.f,0.f,0.f};
#pragma unroll
        for (int kk = 0; kk < 4; ++kk)
            acc = __builtin_amdgcn_mfma_f32_16x16x32_bf16(af[kk], FB[(nt*4+kk)*64 + lane], acc, 0,0,0);
        int col = nt*16 + l15;
        float bb = p.b1a[col], wc = p.w1col[col];
#pragma unroll
        for (int i = 0; i < 4; ++i)
            p.x1[(long)(m0 + quad*4 + i)*256 + col] = (__bf16)fmaxf(acc[i] + bb + wc*sb_i[i], 0.f);
    }
}

// LSTM: gates = x1@Wfold^T + h0@Whh^T + gbias2; elementwise  (4096 units)
__device__ void stage_lstm(const ActP& p, int u, int lane, int quad, int l15){
    int mt = u >> 4, ct = u & 15, m0 = mt*16;
    bf16x8 af[16];
#pragma unroll
    for (int kk = 0; kk < 8; ++kk)
        af[kk] = *(const bf16x8*)&p.x1[(long)(m0 + l15)*256 + kk*32 + quad*8];
#pragma unroll
    for (int kk = 0; kk < 8; ++kk){
        const float4* hp = (const float4*)(p.h0 + (long)(m0 + l15)*256 + kk*32 + quad*8);
        af[8+kk] = pack8(hp[0], hp[1]);
    }
    const bf16x8* FW = (const bf16x8*)(p.wsbf + EL_WFOLD);
    const bf16x8* FH = (const bf16x8*)(p.wsbf + EL_WHH);
    f32x4 aI = {0.f,0.f,0.f,0.f}, aF = aI, aG = aI, aO = aI;
#pragma unroll 4
    for (int kk = 0; kk < 8; ++kk){
        aI = __builtin_amdgcn_mfma_f32_16x16x32_bf16(af[kk], FW[(( 0+ct)*8+kk)*64 + lane], aI, 0,0,0);
        aF = __builtin_amdgcn_mfma_f32_16x16x32_bf16(af[kk], FW[((16+ct)*8+kk)*64 + lane], aF, 0,0,0);
        aG = __builtin_amdgcn_mfma_f32_16x16x32_bf16(af[kk], FW[((32+ct)*8+kk)*64 + lane], aG, 0,0,0);
        aO = __builtin_amdgcn_mfma_f32_16x16x32_bf16(af[kk], FW[((48+ct)*8+kk)*64 + lane], aO, 0,0,0);
    }
#pragma unroll 4
    for (int kk = 0; kk < 8; ++kk){
        aI = __builtin_amdgcn_mfma_f32_16x16x32_bf16(af[8+kk], FH[(( 0+ct)*8+kk)*64 + lane], aI, 0,0,0);
        aF = __builtin_amdgcn_mfma_f32_16x16x32_bf16(af[8+kk], FH[((16+ct)*8+kk)*64 + lane], aF, 0,0,0);
        aG = __builtin_amdgcn_mfma_f32_16x16x32_bf16(af[8+kk], FH[((32+ct)*8+kk)*64 + lane], aG, 0,0,0);
        aO = __builtin_amdgcn_mfma_f32_16x16x32_bf16(af[8+kk], FH[((48+ct)*8+kk)*64 + lane], aO, 0,0,0);
    }
    int col = ct*16 + l15;
    float bI = p.gb2[col], bF = p.gb2[256+col], bG = p.gb2[512+col], bO = p.gb2[768+col];
#pragma unroll
    for (int i = 0; i < 4; ++i){
        long row = m0 + quad*4 + i;
        float iv = aI[i]+bI, fv = aF[i]+bF, gv = aG[i]+bG, ov = aO[i]+bO;
        float cc = p.c0[row*256 + col];
        float cn = sigmoid_f(fv)*cc + sigmoid_f(iv)*tanh_f(gv);
        float hn = sigmoid_f(ov)*tanh_f(cn);
        p.out_c[row*256 + col] = cn;
        p.out_h[row*256 + col] = hn;
        p.hb[row*256 + col] = (__bf16)hn;
    }
}

// TK: t = h@Tm + tb; cst = h.cvec + cbias   (1024 units)
__device__ void stage_tk(const ActP& p, int u, int lane, int quad, int l15){
    int mt = u >> 2, ng = u & 3, m0 = mt*16;
    bf16x8 af[8];
#pragma unroll
    for (int kk = 0; kk < 8; ++kk)
        af[kk] = *(const bf16x8*)&p.hb[(long)(m0 + l15)*256 + kk*32 + quad*8];
    if (ng == 0){
        float s = 0.f;
#pragma unroll
        for (int kk = 0; kk < 8; ++kk)
#pragma unroll
            for (int j = 0; j < 8; ++j)
                s += p.cvec[kk*32 + quad*8 + j] * (float)af[kk][j];
        s += __shfl_xor(s, 16, 64);
        s += __shfl_xor(s, 32, 64);
        if (lane < 16) p.cst[m0 + l15] = s + p.cbias[0];
    }
    const bf16x8* FB = (const bf16x8*)(p.wsbf + EL_TM);
#pragma unroll
    for (int j = 0; j < 4; ++j){
        int nt = ng*4 + j;
        f32x4 acc = {0.f,0.f,0.f,0.f};
#pragma unroll
        for (int kk = 0; kk < 8; ++kk)
            acc = __builtin_amdgcn_mfma_f32_16x16x32_bf16(af[kk], FB[(nt*8+kk)*64 + lane], acc, 0,0,0);
        int col = nt*16 + l15;
        float bb = p.tb[col];
#pragma unroll
        for (int i = 0; i < 4; ++i)
            p.t[(long)(m0 + quad*4 + i)*256 + col] = (__bf16)(acc[i] + bb);
    }
}

// ---- stage kernels: 1 wave per block (proven R4 occupancy shape) ----------
__global__ __launch_bounds__(64) void pre_k (ActP p){ int l = threadIdx.x; stage_pre (p, blockIdx.x, l, l>>4, l&15); }
__global__ __launch_bounds__(64) void s1_k  (ActP p){ int l = threadIdx.x; stage_s1  (p, blockIdx.x, l, l>>4, l&15); }
__global__ __launch_bounds__(64) void lstm_k(ActP p){ int l = threadIdx.x; stage_lstm(p, blockIdx.x, l, l>>4, l&15); }
__global__ __launch_bounds__(64) void tk_k  (ActP p){ int l = threadIdx.x; stage_tk  (p, blockIdx.x, l, l>>4, l&15); }

// ===================== neighbor path (R4 structure, deg-aware) =============
__global__ __launch_bounds__(256) void nei_kernel(
    const float* __restrict__ node_pre, const float* __restrict__ steps,
    const float* __restrict__ b2a, const float* __restrict__ w2col,
    const int* __restrict__ neighbors, const int* __restrict__ deg,
    const __bf16* __restrict__ wsbf, const __bf16* __restrict__ t_bf,
    const float* __restrict__ const_ws, float* __restrict__ out_vals)
{
    __shared__ __bf16 at[64*136];
    __shared__ float t_s[256], bias_s[256], vp[256];

    int tid = threadIdx.x, b = blockIdx.x;
    int degb = deg[b]; if (degb < 1) degb = 1;
    int ntile = (degb + 15) >> 4;
    float sb = steps[b] * 0.01f;
    t_s[tid]    = (float)t_bf[(long)b*256 + tid];
    bias_s[tid] = b2a[tid] + w2col[tid]*sb;
    {
        int r = tid >> 2, sg = tid & 3;
        if (r < ntile*16){
            long nb = neighbors[b*64 + r];
            const float4* sp = (const float4*)(node_pre + nb*128 + sg*32);
#pragma unroll
            for (int q = 0; q < 4; ++q){
                float4 fa = sp[q*2], fb = sp[q*2+1];
                *(bf16x8*)&at[r*136 + sg*32 + q*8] = pack8(fa, fb);
            }
        }
    }

    int wave = tid >> 6, lane = tid & 63, quad = lane >> 4, l15 = lane & 15;
    const bf16x8* FB = (const bf16x8*)(wsbf + EL_W2A);
    bf16x8 bw[16];
#pragma unroll
    for (int j = 0; j < 4; ++j){
        int nt = wave + 4*j;
#pragma unroll
        for (int kk = 0; kk < 4; ++kk) bw[j*4+kk] = FB[(nt*4+kk)*64 + lane];
    }
    __syncthreads();

#pragma unroll 1
    for (int mt = 0; mt < ntile; ++mt){
        bf16x8 af[4];
#pragma unroll
        for (int kk = 0; kk < 4; ++kk)
            af[kk] = *(const bf16x8*)&at[(mt*16 + l15)*136 + kk*32 + quad*8];
        f32x4 ps = {0.f,0.f,0.f,0.f};
#pragma unroll
        for (int j = 0; j < 4; ++j){
            int nt = wave + 4*j;
            f32x4 acc = {0.f,0.f,0.f,0.f};
#pragma unroll
            for (int kk = 0; kk < 4; ++kk)
                acc = __builtin_amdgcn_mfma_f32_16x16x32_bf16(af[kk], bw[j*4+kk], acc, 0,0,0);
            int col = nt*16 + l15;
            float bb = bias_s[col], tv = t_s[col];
#pragma unroll
            for (int i = 0; i < 4; ++i)
                ps[i] += fmaxf(acc[i] + bb, 0.f) * tv;
        }
#pragma unroll
        for (int m = 1; m < 16; m <<= 1){
#pragma unroll
            for (int i = 0; i < 4; ++i) ps[i] += __shfl_xor(ps[i], m, 64);
        }
        if (l15 == 0){
#pragma unroll
            for (int i = 0; i < 4; ++i) vp[wave*64 + mt*16 + quad*4 + i] = ps[i];
        }
    }
    __syncthreads();
    if (tid < 64){
        float v = vp[tid] + vp[64+tid] + vp[128+tid] + vp[192+tid];
        v = (v + const_ws[b]) * 0.08838834764831845f;   // 1/sqrt(128)
        if (tid >= degb) v = 0.f;
        out_vals[(long)b*64 + tid] = v;
    }
}

extern "C" void kernel_launch(void* const* d_in, const int* in_sizes, int n_in,
                              void* d_out, int out_size, void* d_ws, size_t ws_size,
                              hipStream_t stream)
{
    (void)in_sizes; (void)n_in; (void)out_size; (void)ws_size;
    const float* node_pre = (const float*)d_in[0];

    float* out      = (float*)d_out;
    float* out_vals = out;                       // [4096][64]
    float* out_h    = out + (long)BB*KK;         // [4096][256]
    float* out_c    = out_h + (long)BB*HH;       // [4096][256]

    ActP p;
    p.node_pre = node_pre;
    p.steps    = (const float*)d_in[1];
    p.h0       = (const float*)d_in[2];
    p.c0       = (const float*)d_in[3];
    p.W1a      = (const float*)d_in[4];
    p.b1a      = (const float*)d_in[5];
    p.W1b      = (const float*)d_in[6];
    p.b1b      = (const float*)d_in[7];
    p.W2a      = (const float*)d_in[8];
    p.W2b      = (const float*)d_in[10];
    p.b2b      = (const float*)d_in[11];
    p.W3       = (const float*)d_in[12];
    p.b3       = (const float*)d_in[13];
    p.Wih      = (const float*)d_in[14];
    p.Whh      = (const float*)d_in[15];
    p.bih      = (const float*)d_in[16];
    p.bhh      = (const float*)d_in[17];
    p.actions0 = (const int*)d_in[18];
    p.wsbf  = (__bf16*)d_ws;
    p.gb2   = (float*)((char*)d_ws + BOFF_GB2);
    p.w1col = (float*)((char*)d_ws + BOFF_W1COL);
    p.w2col = (float*)((char*)d_ws + BOFF_W2COL);
    p.tb    = (float*)((char*)d_ws + BOFF_TB);
    p.cvec  = (float*)((char*)d_ws + BOFF_CVEC);
    p.cbias = (float*)((char*)d_ws + BOFF_CBIAS);
    p.cst   = (float*)((char*)d_ws + BOFF_CONST);
    p.x1    = (__bf16*)((char*)d_ws + BOFF_X1);
    p.hb    = (__bf16*)((char*)d_ws + BOFF_HB);
    p.t     = (__bf16*)((char*)d_ws + BOFF_T);
    p.out_h = out_h; p.out_c = out_c;

    pre_k <<<dim3(N_PRE), dim3(64), 0, stream>>>(p);
    s1_k  <<<dim3(1024),  dim3(64), 0, stream>>>(p);
    lstm_k<<<dim3(4096),  dim3(64), 0, stream>>>(p);
    tk_k  <<<dim3(1024),  dim3(64), 0, stream>>>(p);

    nei_kernel<<<dim3(4096), dim3(256), 0, stream>>>(
        node_pre, p.steps, (const float*)d_in[9],
        (const float*)((char*)d_ws + BOFF_W2COL),
        (const int*)d_in[19], (const int*)d_in[20],
        (const __bf16*)d_ws, (const __bf16*)((char*)d_ws + BOFF_T),
        (const float*)((char*)d_ws + BOFF_CONST), out_vals);
}

// Round 9
// 210.578 us; speedup vs baseline: 2.8579x; 1.0907x over previous
//
#include <hip/hip_runtime.h>
#include <hip/hip_bf16.h>

// Problem constants
#define NN 100000
#define DD 128
#define BB 4096
#define KK 64
#define HH 256
#define EE 128

typedef __bf16 bf16x8 __attribute__((ext_vector_type(8)));
typedef float f32x4 __attribute__((ext_vector_type(4)));

// ---- bf16 frag region (element offsets). frag = 64 lanes x 16B = 512 elems.
// B-frag layout for mfma_f32_16x16x32_bf16: lane l holds B[k][n] with
// n = nt*16 + (l&15), k = kk*32 + (l>>4)*8 + j, j=0..7.
#define EL_W1A 0        // 16nt x 4kk = 64 frags   (W1a, K=128)
#define EL_W1B 32768    // 8nt x 8kk  = 64 frags   (W1b, K=256)
#define EL_WIH 65536    // 64nt x 4kk = 256 frags  (Wih, K=128)
#define EL_WHH 196608   // 64nt x 8kk = 512 frags  (Whh, K=256)
#define EL_W2A 458752   // 16nt x 4kk = 64 frags   (W2a, K=128)
#define EL_TM  491520   // 16nt x 8kk = 128 frags  (Tm = W3^T-contract-W2b, K=256)
// frag region ends at elem 557056 = byte 0x110000

// ---- workspace regions (byte offsets) ----
#define BOFF_GB    0x110000   // fp32[1024]  bih+bhh
#define BOFF_W1COL 0x111000   // fp32[256]   W1a[:,128]
#define BOFF_W2COL 0x111400   // fp32[256]   W2a[:,128]
#define BOFF_TB    0x111800   // fp32[256]   W2b^T b3
#define BOFF_CVEC  0x111C00   // fp32[256]   W3^T b2b
#define BOFF_CBIAS 0x112000   // fp32[1]     b2b.b3
#define BOFF_CONST 0x112400   // fp32[4096]
#define BOFF_X1    0x116400   // x1  bf16[4096][256] (2MB)
#define BOFF_X     0x316400   // x   bf16[4096][128] (1MB)
#define BOFF_H0B   0x416400   // h0  bf16[4096][256] (2MB)
#define BOFF_HB    0x616400   // h   bf16[4096][256] (2MB)
#define BOFF_T     0x816400   // t   bf16[4096][256] (2MB)

// pre_k block ranges: 960 swz | 128 Tm | 16 gb | 4 w1col | 4 w2col | 4 tb
//                     | 4 cvec | 1 cbias | 2048 h0conv  => 3169 total
#define N_PRE 3169

__device__ __forceinline__ float sigmoid_f(float x){ return 1.0f/(1.0f+__expf(-x)); }
__device__ __forceinline__ float tanh_f(float x){ return 1.0f - 2.0f/(__expf(2.0f*x)+1.0f); }

__device__ __forceinline__ bf16x8 pack8(float4 a, float4 b){
    bf16x8 v;
    v[0]=(__bf16)a.x; v[1]=(__bf16)a.y; v[2]=(__bf16)a.z; v[3]=(__bf16)a.w;
    v[4]=(__bf16)b.x; v[5]=(__bf16)b.y; v[6]=(__bf16)b.z; v[7]=(__bf16)b.w;
    return v;
}

struct ActP {
    const float *node_pre, *steps, *h0, *c0;
    const float *W1a, *b1a, *W1b, *b1b, *W2a, *W2b, *b2b, *W3, *b3;
    const float *Wih, *Whh, *bih, *bhh;
    const int   *actions0;
    __bf16 *wsbf;
    float  *gb, *w1col, *w2col, *tb, *cvec, *cbias, *cst;
    __bf16 *x1, *x, *h0b, *hb, *t;
    float  *out_h, *out_c;
};

// ===================== pre: swizzles + Tm fold + vectors + h0conv ==========
__global__ __launch_bounds__(64) void pre_k(ActP p)
{
    int g = blockIdx.x, lane = threadIdx.x;
    int quad = lane >> 4, l15 = lane & 15;
    if (g < 960){           // plain frag swizzles: 64+64+256+512+64
        const float* src; int stride, nkk, local; long dst;
        if      (g <  64){ src=p.W1a; stride=129; nkk=4; dst=EL_W1A; local=g;     }
        else if (g < 128){ src=p.W1b; stride=256; nkk=8; dst=EL_W1B; local=g-64;  }
        else if (g < 384){ src=p.Wih; stride=128; nkk=4; dst=EL_WIH; local=g-128; }
        else if (g < 896){ src=p.Whh; stride=256; nkk=8; dst=EL_WHH; local=g-384; }
        else             { src=p.W2a; stride=129; nkk=4; dst=EL_W2A; local=g-896; }
        int nt = local / nkk, kk = local % nkk;
        int n = nt*16 + l15, k0 = kk*32 + quad*8;
        bf16x8 v;
#pragma unroll
        for (int j = 0; j < 8; ++j) v[j] = (__bf16)src[(long)n*stride + k0 + j];
        ((bf16x8*)(p.wsbf + dst))[local*64 + lane] = v;
    }
    else if (g < 1088){     // Tm[m,h] = sum_e W3[e,m]*W2b[e,h] -> frags
        int c = (g-960)*64 + lane;
        int hcol = c >> 5, m8 = c & 31, m0 = m8*8;
        float acc[8] = {0,0,0,0,0,0,0,0};
        for (int e = 0; e < 128; ++e){
            float w = p.W2b[(long)e*256 + hcol];
            const float4* wp = (const float4*)(p.W3 + (long)e*256 + m0);
            float4 a0 = wp[0], a1 = wp[1];
            acc[0] += w*a0.x; acc[1] += w*a0.y; acc[2] += w*a0.z; acc[3] += w*a0.w;
            acc[4] += w*a1.x; acc[5] += w*a1.y; acc[6] += w*a1.z; acc[7] += w*a1.w;
        }
        bf16x8 v;
#pragma unroll
        for (int j = 0; j < 8; ++j) v[j] = (__bf16)acc[j];
        int nt = hcol >> 4, l15r = hcol & 15, kk = m8 >> 2, qd = m8 & 3;
        ((bf16x8*)(p.wsbf + EL_TM))[(nt*8+kk)*64 + qd*16 + l15r] = v;
    }
    else if (g < 1104){ int i = (g-1088)*64 + lane; p.gb[i] = p.bih[i] + p.bhh[i]; }
    else if (g < 1108){ int i = (g-1104)*64 + lane; p.w1col[i] = p.W1a[i*129 + 128]; }
    else if (g < 1112){ int i = (g-1108)*64 + lane; p.w2col[i] = p.W2a[i*129 + 128]; }
    else if (g < 1116){     // tb[h] = sum_e W2b[e,h]*b3[e]
        int i = (g-1112)*64 + lane;
        float s = 0.f;
        for (int e = 0; e < 128; ++e) s += p.W2b[(long)e*256 + i]*p.b3[e];
        p.tb[i] = s;
    }
    else if (g < 1120){     // cvec[m] = sum_e b2b[e]*W3[e,m]
        int i = (g-1116)*64 + lane;
        float s = 0.f;
        for (int e = 0; e < 128; ++e) s += p.b2b[e]*p.W3[(long)e*256 + i];
        p.cvec[i] = s;
    }
    else if (g == 1120){    // cbias = b2b.b3
        float s = p.b2b[lane]*p.b3[lane] + p.b2b[lane+64]*p.b3[lane+64];
#pragma unroll
        for (int m = 1; m < 64; m <<= 1) s += __shfl_xor(s, m, 64);
        if (lane == 0) p.cbias[0] = s;
    }
    else {                  // h0 fp32 -> bf16: 131072 chunks of 8 (2048 blocks)
        long i = (long)(g-1121)*64 + lane;
        const float4* sp = (const float4*)p.h0 + i*2;
        ((bf16x8*)p.h0b)[i] = pack8(sp[0], sp[1]);
    }
}

// XCD-aware decode: units sharing an M-tile land on one XCD (blk%8 heuristic)
__device__ __forceinline__ void xcd_decode(int blk, int nsub, int& mt, int& sub){
    int xcd = blk & 7, r = blk >> 3;
    sub = r % nsub;
    mt  = (r / nsub)*8 + xcd;
}

// ===================== S1: x1 = relu(a_pre @ W1a^T + b1a + w1col*sb) =======
__global__ __launch_bounds__(64) void s1_k(ActP p)
{
    int lane = threadIdx.x, quad = lane >> 4, l15 = lane & 15;
    int mt, ng; xcd_decode(blockIdx.x, 4, mt, ng);
    int m0 = mt*16;
    long arow = p.actions0[m0 + l15];
    bf16x8 af[4];
#pragma unroll
    for (int kk = 0; kk < 4; ++kk){
        const float4* q = (const float4*)(p.node_pre + arow*128 + kk*32 + quad*8);
        af[kk] = pack8(q[0], q[1]);
    }
    float sb_i[4];
#pragma unroll
    for (int i = 0; i < 4; ++i) sb_i[i] = p.steps[m0 + quad*4 + i] * 0.01f;
    const bf16x8* FB = (const bf16x8*)(p.wsbf + EL_W1A);
#pragma unroll
    for (int j = 0; j < 4; ++j){
        int nt = ng*4 + j;
        f32x4 acc = {0.f,0.f,0.f,0.f};
#pragma unroll
        for (int kk = 0; kk < 4; ++kk)
            acc = __builtin_amdgcn_mfma_f32_16x16x32_bf16(af[kk], FB[(nt*4+kk)*64 + lane], acc, 0,0,0);
        int col = nt*16 + l15;
        float bb = p.b1a[col], wc = p.w1col[col];
#pragma unroll
        for (int i = 0; i < 4; ++i)
            p.x1[(long)(m0 + quad*4 + i)*256 + col] = (__bf16)fmaxf(acc[i] + bb + wc*sb_i[i], 0.f);
    }
}

// ===================== S2: x = x1 @ W1b^T + b1b ============================
__global__ __launch_bounds__(64) void s2_k(ActP p)
{
    int lane = threadIdx.x, quad = lane >> 4, l15 = lane & 15;
    int mt, ng; xcd_decode(blockIdx.x, 4, mt, ng);
    int m0 = mt*16;
    bf16x8 af[8];
#pragma unroll
    for (int kk = 0; kk < 8; ++kk)
        af[kk] = *(const bf16x8*)&p.x1[(long)(m0 + l15)*256 + kk*32 + quad*8];
    const bf16x8* FB = (const bf16x8*)(p.wsbf + EL_W1B);
#pragma unroll
    for (int j = 0; j < 2; ++j){
        int nt = ng*2 + j;
        f32x4 acc = {0.f,0.f,0.f,0.f};
#pragma unroll
        for (int kk = 0; kk < 8; ++kk)
            acc = __builtin_amdgcn_mfma_f32_16x16x32_bf16(af[kk], FB[(nt*8+kk)*64 + lane], acc, 0,0,0);
        int col = nt*16 + l15;
        float bb = p.b1b[col];
#pragma unroll
        for (int i = 0; i < 4; ++i)
            p.x[(long)(m0 + quad*4 + i)*128 + col] = (__bf16)(acc[i] + bb);
    }
}

// ===================== LSTM: 4 ct per wave, A-frags persistent =============
__global__ __launch_bounds__(64) void lstm_k(ActP p)
{
    int lane = threadIdx.x, quad = lane >> 4, l15 = lane & 15;
    int mt, ctg; xcd_decode(blockIdx.x, 4, mt, ctg);
    int m0 = mt*16;
    bf16x8 af[12];
#pragma unroll
    for (int kk = 0; kk < 4; ++kk)
        af[kk] = *(const bf16x8*)&p.x[(long)(m0 + l15)*128 + kk*32 + quad*8];
#pragma unroll
    for (int kk = 0; kk < 8; ++kk)
        af[4+kk] = *(const bf16x8*)&p.h0b[(long)(m0 + l15)*256 + kk*32 + quad*8];

    const bf16x8* FIH = (const bf16x8*)(p.wsbf + EL_WIH);
    const bf16x8* FHH = (const bf16x8*)(p.wsbf + EL_WHH);

#pragma unroll 1
    for (int ct2 = 0; ct2 < 4; ++ct2){
        int ct = ctg*4 + ct2;
        f32x4 aI = {0.f,0.f,0.f,0.f}, aF = aI, aG = aI, aO = aI;
#pragma unroll
        for (int kk = 0; kk < 4; ++kk){
            aI = __builtin_amdgcn_mfma_f32_16x16x32_bf16(af[kk], FIH[(( 0+ct)*4+kk)*64 + lane], aI, 0,0,0);
            aF = __builtin_amdgcn_mfma_f32_16x16x32_bf16(af[kk], FIH[((16+ct)*4+kk)*64 + lane], aF, 0,0,0);
            aG = __builtin_amdgcn_mfma_f32_16x16x32_bf16(af[kk], FIH[((32+ct)*4+kk)*64 + lane], aG, 0,0,0);
            aO = __builtin_amdgcn_mfma_f32_16x16x32_bf16(af[kk], FIH[((48+ct)*4+kk)*64 + lane], aO, 0,0,0);
        }
#pragma unroll 4
        for (int k2 = 0; k2 < 8; ++k2){
            aI = __builtin_amdgcn_mfma_f32_16x16x32_bf16(af[4+k2], FHH[(( 0+ct)*8+k2)*64 + lane], aI, 0,0,0);
            aF = __builtin_amdgcn_mfma_f32_16x16x32_bf16(af[4+k2], FHH[((16+ct)*8+k2)*64 + lane], aF, 0,0,0);
            aG = __builtin_amdgcn_mfma_f32_16x16x32_bf16(af[4+k2], FHH[((32+ct)*8+k2)*64 + lane], aG, 0,0,0);
            aO = __builtin_amdgcn_mfma_f32_16x16x32_bf16(af[4+k2], FHH[((48+ct)*8+k2)*64 + lane], aO, 0,0,0);
        }
        int col = ct*16 + l15;
        float bI = p.gb[col], bF = p.gb[256+col], bG = p.gb[512+col], bO = p.gb[768+col];
#pragma unroll
        for (int i = 0; i < 4; ++i){
            long row = m0 + quad*4 + i;
            float iv = aI[i]+bI, fv = aF[i]+bF, gv = aG[i]+bG, ov = aO[i]+bO;
            float cc = p.c0[row*256 + col];
            float cn = sigmoid_f(fv)*cc + sigmoid_f(iv)*tanh_f(gv);
            float hn = sigmoid_f(ov)*tanh_f(cn);
            p.out_c[row*256 + col] = cn;
            p.out_h[row*256 + col] = hn;
            p.hb[row*256 + col] = (__bf16)hn;
        }
    }
}

// ===================== TK: t = h@Tm + tb; cst = h.cvec + cbias =============
__global__ __launch_bounds__(64) void tk_k(ActP p)
{
    int lane = threadIdx.x, quad = lane >> 4, l15 = lane & 15;
    int mt, ng; xcd_decode(blockIdx.x, 4, mt, ng);
    int m0 = mt*16;
    bf16x8 af[8];
#pragma unroll
    for (int kk = 0; kk < 8; ++kk)
        af[kk] = *(const bf16x8*)&p.hb[(long)(m0 + l15)*256 + kk*32 + quad*8];
    if (ng == 0){
        float s = 0.f;
#pragma unroll
        for (int kk = 0; kk < 8; ++kk)
#pragma unroll
            for (int j = 0; j < 8; ++j)
                s += p.cvec[kk*32 + quad*8 + j] * (float)af[kk][j];
        s += __shfl_xor(s, 16, 64);
        s += __shfl_xor(s, 32, 64);
        if (lane < 16) p.cst[m0 + l15] = s + p.cbias[0];
    }
    const bf16x8* FB = (const bf16x8*)(p.wsbf + EL_TM);
#pragma unroll
    for (int j = 0; j < 4; ++j){
        int nt = ng*4 + j;
        f32x4 acc = {0.f,0.f,0.f,0.f};
#pragma unroll
        for (int kk = 0; kk < 8; ++kk)
            acc = __builtin_amdgcn_mfma_f32_16x16x32_bf16(af[kk], FB[(nt*8+kk)*64 + lane], acc, 0,0,0);
        int col = nt*16 + l15;
        float bb = p.tb[col];
#pragma unroll
        for (int i = 0; i < 4; ++i)
            p.t[(long)(m0 + quad*4 + i)*256 + col] = (__bf16)(acc[i] + bb);
    }
}

// ===================== neighbor path (R4 structure, deg-aware) =============
__global__ __launch_bounds__(256) void nei_kernel(
    const float* __restrict__ node_pre, const float* __restrict__ steps,
    const float* __restrict__ b2a, const float* __restrict__ w2col,
    const int* __restrict__ neighbors, const int* __restrict__ deg,
    const __bf16* __restrict__ wsbf, const __bf16* __restrict__ t_bf,
    const float* __restrict__ const_ws, float* __restrict__ out_vals)
{
    __shared__ __bf16 at[64*136];
    __shared__ float t_s[256], bias_s[256], vp[256];

    int tid = threadIdx.x, b = blockIdx.x;
    int degb = deg[b]; if (degb < 1) degb = 1;
    int ntile = (degb + 15) >> 4;
    float sb = steps[b] * 0.01f;
    t_s[tid]    = (float)t_bf[(long)b*256 + tid];
    bias_s[tid] = b2a[tid] + w2col[tid]*sb;
    {
        int r = tid >> 2, sg = tid & 3;
        if (r < ntile*16){
            long nb = neighbors[b*64 + r];
            const float4* sp = (const float4*)(node_pre + nb*128 + sg*32);
#pragma unroll
            for (int q = 0; q < 4; ++q){
                float4 fa = sp[q*2], fb = sp[q*2+1];
                *(bf16x8*)&at[r*136 + sg*32 + q*8] = pack8(fa, fb);
            }
        }
    }

    int wave = tid >> 6, lane = tid & 63, quad = lane >> 4, l15 = lane & 15;
    const bf16x8* FB = (const bf16x8*)(wsbf + EL_W2A);
    bf16x8 bw[16];
#pragma unroll
    for (int j = 0; j < 4; ++j){
        int nt = wave + 4*j;
#pragma unroll
        for (int kk = 0; kk < 4; ++kk) bw[j*4+kk] = FB[(nt*4+kk)*64 + lane];
    }
    __syncthreads();

#pragma unroll 1
    for (int mt = 0; mt < ntile; ++mt){
        bf16x8 af[4];
#pragma unroll
        for (int kk = 0; kk < 4; ++kk)
            af[kk] = *(const bf16x8*)&at[(mt*16 + l15)*136 + kk*32 + quad*8];
        f32x4 ps = {0.f,0.f,0.f,0.f};
#pragma unroll
        for (int j = 0; j < 4; ++j){
            int nt = wave + 4*j;
            f32x4 acc = {0.f,0.f,0.f,0.f};
#pragma unroll
            for (int kk = 0; kk < 4; ++kk)
                acc = __builtin_amdgcn_mfma_f32_16x16x32_bf16(af[kk], bw[j*4+kk], acc, 0,0,0);
            int col = nt*16 + l15;
            float bb = bias_s[col], tv = t_s[col];
#pragma unroll
            for (int i = 0; i < 4; ++i)
                ps[i] += fmaxf(acc[i] + bb, 0.f) * tv;
        }
#pragma unroll
        for (int m = 1; m < 16; m <<= 1){
#pragma unroll
            for (int i = 0; i < 4; ++i) ps[i] += __shfl_xor(ps[i], m, 64);
        }
        if (l15 == 0){
#pragma unroll
            for (int i = 0; i < 4; ++i) vp[wave*64 + mt*16 + quad*4 + i] = ps[i];
        }
    }
    __syncthreads();
    if (tid < 64){
        float v = vp[tid] + vp[64+tid] + vp[128+tid] + vp[192+tid];
        v = (v + const_ws[b]) * 0.08838834764831845f;   // 1/sqrt(128)
        if (tid >= degb) v = 0.f;
        out_vals[(long)b*64 + tid] = v;
    }
}

extern "C" void kernel_launch(void* const* d_in, const int* in_sizes, int n_in,
                              void* d_out, int out_size, void* d_ws, size_t ws_size,
                              hipStream_t stream)
{
    (void)in_sizes; (void)n_in; (void)out_size; (void)ws_size;
    const float* node_pre = (const float*)d_in[0];

    float* out      = (float*)d_out;
    float* out_vals = out;                       // [4096][64]
    float* out_h    = out + (long)BB*KK;         // [4096][256]
    float* out_c    = out_h + (long)BB*HH;       // [4096][256]

    ActP p;
    p.node_pre = node_pre;
    p.steps    = (const float*)d_in[1];
    p.h0       = (const float*)d_in[2];
    p.c0       = (const float*)d_in[3];
    p.W1a      = (const float*)d_in[4];
    p.b1a      = (const float*)d_in[5];
    p.W1b      = (const float*)d_in[6];
    p.b1b      = (const float*)d_in[7];
    p.W2a      = (const float*)d_in[8];
    p.W2b      = (const float*)d_in[10];
    p.b2b      = (const float*)d_in[11];
    p.W3       = (const float*)d_in[12];
    p.b3       = (const float*)d_in[13];
    p.Wih      = (const float*)d_in[14];
    p.Whh      = (const float*)d_in[15];
    p.bih      = (const float*)d_in[16];
    p.bhh      = (const float*)d_in[17];
    p.actions0 = (const int*)d_in[18];
    p.wsbf  = (__bf16*)d_ws;
    p.gb    = (float*)((char*)d_ws + BOFF_GB);
    p.w1col = (float*)((char*)d_ws + BOFF_W1COL);
    p.w2col = (float*)((char*)d_ws + BOFF_W2COL);
    p.tb    = (float*)((char*)d_ws + BOFF_TB);
    p.cvec  = (float*)((char*)d_ws + BOFF_CVEC);
    p.cbias = (float*)((char*)d_ws + BOFF_CBIAS);
    p.cst   = (float*)((char*)d_ws + BOFF_CONST);
    p.x1    = (__bf16*)((char*)d_ws + BOFF_X1);
    p.x     = (__bf16*)((char*)d_ws + BOFF_X);
    p.h0b   = (__bf16*)((char*)d_ws + BOFF_H0B);
    p.hb    = (__bf16*)((char*)d_ws + BOFF_HB);
    p.t     = (__bf16*)((char*)d_ws + BOFF_T);
    p.out_h = out_h; p.out_c = out_c;

    pre_k <<<dim3(N_PRE), dim3(64), 0, stream>>>(p);
    s1_k  <<<dim3(1024),  dim3(64), 0, stream>>>(p);
    s2_k  <<<dim3(1024),  dim3(64), 0, stream>>>(p);
    lstm_k<<<dim3(1024),  dim3(64), 0, stream>>>(p);
    tk_k  <<<dim3(1024),  dim3(64), 0, stream>>>(p);

    nei_kernel<<<dim3(4096), dim3(256), 0, stream>>>(
        node_pre, p.steps, (const float*)d_in[9],
        (const float*)((char*)d_ws + BOFF_W2COL),
        (const int*)d_in[19], (const int*)d_in[20],
        (const __bf16*)d_ws, (const __bf16*)((char*)d_ws + BOFF_T),
        (const float*)((char*)d_ws + BOFF_CONST), out_vals);
}